// Round 5
// baseline (571.803 us; speedup 1.0000x reference)
//
#include <hip/hip_runtime.h>

#define N_ENTITIES 500000
#define N_RELS 1000
#define EMB_DIM 128
#define N_TRIPLES 1000000

// ---- fused segmented-argmax find+join ----
// 250 blocks x 1024 threads; block b owns entities [b*2000, b*2000+2000).
// Each block streams ALL of h_idx (4 MB; L2/L3-resident after first pass),
// LDS-atomicMax in-range triple ids, then joins r/t and writes its pack
// slice. No device-scope atomics (measured flat ~6 G/s = ~165 us for 1M),
// no init pass, and workspace need is ONLY the 4 MB pack table (rounds 1-4
// prove >=4 MB exists; larger budgets were never observable).
#define N_SEG_BLOCKS 250
#define SEG_ENT (N_ENTITIES / N_SEG_BLOCKS)   // 2000 exact, 8 KB LDS
#define FIND_THREADS 1024

// ---- apply tiling (unchanged from round 2; byte-identical kernel) ----
#define STEPS 4
#define ROWS_PER_STEP 8
#define BLOCK_ROWS (STEPS * ROWS_PER_STEP)    // 32; 500000/32 = 15625 blocks

typedef float floatx4 __attribute__((ext_vector_type(4)));
typedef unsigned long long u64;

// pack[v]: (e+1)<<29 | r<<19 | t   (t < 2^19, r < 2^10, e+1 < 2^20); 0 = none.
// max over e == last-write-wins; per-entity owner block => deterministic.

__global__ __launch_bounds__(FIND_THREADS)
void find_pack_kernel(const int4* __restrict__ h4,
                      const int* __restrict__ r_idx,
                      const int* __restrict__ t_idx,
                      u64* __restrict__ pack) {
    __shared__ int best[SEG_ENT];
    int tid = threadIdx.x;
    int lo  = blockIdx.x * SEG_ENT;

    for (int i = tid; i < SEG_ENT; i += FIND_THREADS) best[i] = -1;
    __syncthreads();

    const int QUADS = N_TRIPLES / 4;
    for (int q = tid; q < QUADS; q += FIND_THREADS) {
        int4 h = h4[q];                        // coalesced 16 KB per wave-iter
        int e = 4 * q;
        unsigned a;
        a = (unsigned)(h.x - lo); if (a < (unsigned)SEG_ENT) atomicMax(&best[a], e);
        a = (unsigned)(h.y - lo); if (a < (unsigned)SEG_ENT) atomicMax(&best[a], e + 1);
        a = (unsigned)(h.z - lo); if (a < (unsigned)SEG_ENT) atomicMax(&best[a], e + 2);
        a = (unsigned)(h.w - lo); if (a < (unsigned)SEG_ENT) atomicMax(&best[a], e + 3);
    }
    __syncthreads();

    for (int i = tid; i < SEG_ENT; i += FIND_THREADS) {
        int w = best[i];
        u64 key = 0ull;
        if (w >= 0) {
            u64 r = (u64)(unsigned)r_idx[w];   // random 4B, L2/L3-warm tables
            u64 t = (u64)(unsigned)t_idx[w];
            key = ((u64)(w + 1) << 29) | (r << 19) | t;
        }
        pack[lo + i] = key;                    // coalesced 16 KB slice
    }
}

// ---- apply: byte-identical to round 2/3 (measured <153 us) ----
__global__ void apply_kernel(const float* __restrict__ memory,
                             const float* __restrict__ rel_table,
                             const u64* __restrict__ pack,
                             float* __restrict__ out) {
    int lane = threadIdx.x & 31;
    int hr   = threadIdx.x >> 5;
    int base = blockIdx.x * BLOCK_ROWS;

    int rows[STEPS];
    u64 k[STEPS];
#pragma unroll
    for (int i = 0; i < STEPS; ++i) {
        rows[i] = base + i * ROWS_PER_STEP + hr;
        k[i] = __builtin_nontemporal_load(&pack[rows[i]]);
    }

    floatx4 h[STEPS];
#pragma unroll
    for (int i = 0; i < STEPS; ++i)
        h[i] = ((const floatx4*)(memory + (size_t)rows[i] * EMB_DIM))[lane];

    floatx4 rv[STEPS], tv[STEPS];
#pragma unroll
    for (int i = 0; i < STEPS; ++i) {
        int t = (int)(k[i] & 0x7FFFF);
        int r = (int)((k[i] >> 19) & 0x3FF);
        rv[i] = ((const floatx4*)(rel_table + (size_t)r * EMB_DIM))[lane];
        tv[i] = ((const floatx4*)(memory    + (size_t)t * EMB_DIM))[lane];
    }

#pragma unroll
    for (int i = 0; i < STEPS; ++i) {
        floatx4 upd = 0.9f * h[i] + 0.1f * (h[i] + rv[i] - tv[i]);
        floatx4 val = (k[i] != 0ull) ? upd : h[i];
        floatx4* orow = (floatx4*)(out + (size_t)rows[i] * EMB_DIM) + lane;
        __builtin_nontemporal_store(val, orow);
    }
}

extern "C" void kernel_launch(void* const* d_in, const int* in_sizes, int n_in,
                              void* d_out, int out_size, void* d_ws, size_t ws_size,
                              hipStream_t stream) {
    const float* memory    = (const float*)d_in[0];
    const float* rel_table = (const float*)d_in[1];
    const int*   h_idx     = (const int*)d_in[2];
    const int*   r_idx     = (const int*)d_in[3];
    const int*   t_idx     = (const int*)d_in[4];
    float*       out       = (float*)d_out;

    u64* pack = (u64*)d_ws;                    // 4 MB — fits proven ws budget

    find_pack_kernel<<<N_SEG_BLOCKS, FIND_THREADS, 0, stream>>>(
        (const int4*)h_idx, r_idx, t_idx, pack);

    apply_kernel<<<N_ENTITIES / BLOCK_ROWS, 256, 0, stream>>>(
        memory, rel_table, pack, out);
}

// Round 6
// 487.787 us; speedup vs baseline: 1.1722x; 1.1722x over previous
//
#include <hip/hip_runtime.h>

#define N_ENTITIES 500000
#define N_RELS 1000
#define EMB_DIM 128
#define N_TRIPLES 1000000

// Apply tiling: each 256-thread block owns a contiguous 40-row tile
// (40 x 512 B = 20 KB); step i covers 8 consecutive rows (one per half-wave).
// 500000 / 40 = 12500 blocks exactly.
#define STEPS 5
#define ROWS_PER_STEP 8
#define BLOCK_ROWS (STEPS * ROWS_PER_STEP)   // 40

typedef float floatx4 __attribute__((ext_vector_type(4)));
typedef unsigned long long u64;

// pack[v]: (e+1)<<29 | r<<19 | t   (t < 2^19, r < 2^10, e+1 < 2^20); 0 = none.
// max over keys == max over e (e in high bits) => last-write-wins,
// order-independent => deterministic under graph replay.
//
// Accounting correction (r5): the timed window contains ~314 us of harness
// 1-GB poison fills; atomic find was ALWAYS ~15 us (r0-r4 variants all flat).
// Plain device-scope atomic pre-join is the simplest proven find -- keep it.

__global__ void init_pack_kernel(ulonglong2* __restrict__ pack2, int n2) {
    int i = blockIdx.x * blockDim.x + threadIdx.x;
    if (i < n2) { ulonglong2 z; z.x = 0ull; z.y = 0ull; pack2[i] = z; }
}

__global__ void find_winner_kernel(const int4* __restrict__ h4,
                                   const int4* __restrict__ r4,
                                   const int4* __restrict__ t4,
                                   u64* __restrict__ pack) {
    int q = blockIdx.x * blockDim.x + threadIdx.x;
    if (q >= N_TRIPLES / 4) return;
    int4 h = h4[q]; int4 r = r4[q]; int4 t = t4[q];
    u64 e1 = (u64)(4 * q + 1);
    atomicMax(&pack[h.x], (e1      << 29) | ((u64)r.x << 19) | (u64)t.x);
    atomicMax(&pack[h.y], ((e1 + 1) << 29) | ((u64)r.y << 19) | (u64)t.y);
    atomicMax(&pack[h.z], ((e1 + 2) << 29) | ((u64)r.z << 19) | (u64)t.z);
    atomicMax(&pack[h.w], ((e1 + 3) << 29) | ((u64)r.w << 19) | (u64)t.w);
}

// Apply: per thread 5 rows in the block's contiguous 40-row tile.
// Issue order is the change under test: pack -> ALL rv/tv gathers -> h-stream
// -> combine. The random L3 gathers (~600 cy) launch first so their latency
// hides under the sequential h-stream, instead of serializing after it.
// h loads stay regular (L3-allocating: memory's L3 residency is what makes
// t-gathers HBM-free); out-stores stay nontemporal (don't evict memory).
__global__ void apply_kernel(const float* __restrict__ memory,
                             const float* __restrict__ rel_table,
                             const u64* __restrict__ pack,
                             float* __restrict__ out) {
    int lane = threadIdx.x & 31;
    int hr   = threadIdx.x >> 5;
    int base = blockIdx.x * BLOCK_ROWS;

    int rows[STEPS];
    u64 k[STEPS];
#pragma unroll
    for (int i = 0; i < STEPS; ++i) {
        rows[i] = base + i * ROWS_PER_STEP + hr;
        k[i] = __builtin_nontemporal_load(&pack[rows[i]]);
    }

    // Random gathers first: longest-latency loads go in flight earliest.
    floatx4 rv[STEPS], tv[STEPS];
#pragma unroll
    for (int i = 0; i < STEPS; ++i) {
        int t = (int)(k[i] & 0x7FFFF);              // row 0 when no winner
        int r = (int)((k[i] >> 19) & 0x3FF);        // rel 0 when no winner
        rv[i] = ((const floatx4*)(rel_table + (size_t)r * EMB_DIM))[lane];
        tv[i] = ((const floatx4*)(memory    + (size_t)t * EMB_DIM))[lane];
    }

    // Sequential h-stream flows while gathers are outstanding.
    floatx4 h[STEPS];
#pragma unroll
    for (int i = 0; i < STEPS; ++i)
        h[i] = ((const floatx4*)(memory + (size_t)rows[i] * EMB_DIM))[lane];

#pragma unroll
    for (int i = 0; i < STEPS; ++i) {
        // Exact arithmetic for winner rows; exact h passthrough otherwise.
        floatx4 upd = 0.9f * h[i] + 0.1f * (h[i] + rv[i] - tv[i]);
        floatx4 val = (k[i] != 0ull) ? upd : h[i];
        floatx4* orow = (floatx4*)(out + (size_t)rows[i] * EMB_DIM) + lane;
        __builtin_nontemporal_store(val, orow);
    }
}

extern "C" void kernel_launch(void* const* d_in, const int* in_sizes, int n_in,
                              void* d_out, int out_size, void* d_ws, size_t ws_size,
                              hipStream_t stream) {
    const float* memory    = (const float*)d_in[0];
    const float* rel_table = (const float*)d_in[1];
    const int*   h_idx     = (const int*)d_in[2];
    const int*   r_idx     = (const int*)d_in[3];
    const int*   t_idx     = (const int*)d_in[4];
    float*       out       = (float*)d_out;

    u64* pack = (u64*)d_ws;                        // 4 MB

    {
        int n2 = N_ENTITIES / 2;
        init_pack_kernel<<<(n2 + 255) / 256, 256, 0, stream>>>(
            (ulonglong2*)pack, n2);
    }
    find_winner_kernel<<<(N_TRIPLES / 4 + 255) / 256, 256, 0, stream>>>(
        (const int4*)h_idx, (const int4*)r_idx, (const int4*)t_idx, pack);

    apply_kernel<<<N_ENTITIES / BLOCK_ROWS, 256, 0, stream>>>(
        memory, rel_table, pack, out);
}

// Round 8
// 487.620 us; speedup vs baseline: 1.1726x; 1.0003x over previous
//
#include <hip/hip_runtime.h>

#define N_ENTITIES 500000
#define N_RELS 1000
#define EMB_DIM 128
#define N_TRIPLES 1000000

// Apply tiling: each 256-thread block owns a contiguous 40-row tile
// (40 x 512 B = 20 KB); step i covers 8 consecutive rows (one per half-wave).
// 500000 / 40 = 12500 blocks exactly.
#define STEPS 5
#define ROWS_PER_STEP 8
#define BLOCK_ROWS (STEPS * ROWS_PER_STEP)   // 40

typedef float floatx4 __attribute__((ext_vector_type(4)));
typedef unsigned long long u64;

// pack[v]: (e+1)<<29 | r<<19 | t   (t < 2^19, r < 2^10, e+1 < 2^20); 0 = none.
// max over keys == max over e (e in high bits) => last-write-wins,
// order-independent => deterministic under graph replay.
//
// Budget (corrected r5/r6): ~314 us harness poison fills (untouchable) +
// find/init ~13 us + apply ~158 us. Apply is the only lever. This round's
// single-variable A/B: regular stores instead of nontemporal (NT inherited
// untested from r0; harness fill sustains 6.5 TB/s with regular stores).
// (Round 7 was a broker timeout; this is the same kernel resubmitted.)

__global__ void init_pack_kernel(ulonglong2* __restrict__ pack2, int n2) {
    int i = blockIdx.x * blockDim.x + threadIdx.x;
    if (i < n2) { ulonglong2 z; z.x = 0ull; z.y = 0ull; pack2[i] = z; }
}

__global__ void find_winner_kernel(const int4* __restrict__ h4,
                                   const int4* __restrict__ r4,
                                   const int4* __restrict__ t4,
                                   u64* __restrict__ pack) {
    int q = blockIdx.x * blockDim.x + threadIdx.x;
    if (q >= N_TRIPLES / 4) return;
    int4 h = h4[q]; int4 r = r4[q]; int4 t = t4[q];
    u64 e1 = (u64)(4 * q + 1);
    atomicMax(&pack[h.x], (e1      << 29) | ((u64)r.x << 19) | (u64)t.x);
    atomicMax(&pack[h.y], ((e1 + 1) << 29) | ((u64)r.y << 19) | (u64)t.y);
    atomicMax(&pack[h.z], ((e1 + 2) << 29) | ((u64)r.z << 19) | (u64)t.z);
    atomicMax(&pack[h.w], ((e1 + 3) << 29) | ((u64)r.w << 19) | (u64)t.w);
}

// Apply: identical to round 6 EXCEPT the out-store is a plain (L2/L3-
// allocating) store, not __builtin_nontemporal_store. Everything else held
// fixed for a clean A/B. Failure signature if L3 pollution hurts gathers:
// FETCH_SIZE rises well above ~243e3 with time flat or worse.
__global__ void apply_kernel(const float* __restrict__ memory,
                             const float* __restrict__ rel_table,
                             const u64* __restrict__ pack,
                             float* __restrict__ out) {
    int lane = threadIdx.x & 31;
    int hr   = threadIdx.x >> 5;
    int base = blockIdx.x * BLOCK_ROWS;

    int rows[STEPS];
    u64 k[STEPS];
#pragma unroll
    for (int i = 0; i < STEPS; ++i) {
        rows[i] = base + i * ROWS_PER_STEP + hr;
        k[i] = __builtin_nontemporal_load(&pack[rows[i]]);
    }

    floatx4 rv[STEPS], tv[STEPS];
#pragma unroll
    for (int i = 0; i < STEPS; ++i) {
        int t = (int)(k[i] & 0x7FFFF);              // row 0 when no winner
        int r = (int)((k[i] >> 19) & 0x3FF);        // rel 0 when no winner
        rv[i] = ((const floatx4*)(rel_table + (size_t)r * EMB_DIM))[lane];
        tv[i] = ((const floatx4*)(memory    + (size_t)t * EMB_DIM))[lane];
    }

    floatx4 h[STEPS];
#pragma unroll
    for (int i = 0; i < STEPS; ++i)
        h[i] = ((const floatx4*)(memory + (size_t)rows[i] * EMB_DIM))[lane];

#pragma unroll
    for (int i = 0; i < STEPS; ++i) {
        // Exact arithmetic for winner rows; exact h passthrough otherwise.
        floatx4 upd = 0.9f * h[i] + 0.1f * (h[i] + rv[i] - tv[i]);
        floatx4 val = (k[i] != 0ull) ? upd : h[i];
        floatx4* orow = (floatx4*)(out + (size_t)rows[i] * EMB_DIM) + lane;
        *orow = val;                                 // regular store (A/B vs NT)
    }
}

extern "C" void kernel_launch(void* const* d_in, const int* in_sizes, int n_in,
                              void* d_out, int out_size, void* d_ws, size_t ws_size,
                              hipStream_t stream) {
    const float* memory    = (const float*)d_in[0];
    const float* rel_table = (const float*)d_in[1];
    const int*   h_idx     = (const int*)d_in[2];
    const int*   r_idx     = (const int*)d_in[3];
    const int*   t_idx     = (const int*)d_in[4];
    float*       out       = (float*)d_out;

    u64* pack = (u64*)d_ws;                        // 4 MB

    {
        int n2 = N_ENTITIES / 2;
        init_pack_kernel<<<(n2 + 255) / 256, 256, 0, stream>>>(
            (ulonglong2*)pack, n2);
    }
    find_winner_kernel<<<(N_TRIPLES / 4 + 255) / 256, 256, 0, stream>>>(
        (const int4*)h_idx, (const int4*)r_idx, (const int4*)t_idx, pack);

    apply_kernel<<<N_ENTITIES / BLOCK_ROWS, 256, 0, stream>>>(
        memory, rel_table, pack, out);
}